// Round 22
// baseline (46.963 us; speedup 1.0000x reference)
//
#include <hip/hip_runtime.h>

// ConvDatapath: bit-serial crossbar conv with per-chunk ADC quantization.
// R21 state: k_q = 15.3us + k_d = 18.6us. This round FOLDS x-quant into the
// matmul kernel: each block quantizes its rtile's 16 x-rows into LDS rows
// (656-stride, R8-proven fragment-readable) — Xq global roundtrip deleted.
// k_wq  : 32 blocks, one w-row per wave (R21 v4 verbatim) -> fragment Wq.
// k_main: 1568 blocks x 256 thr = (rtile, cquad of 2 ctiles). 4 waves:
//         each quantizes 4 x-rows (R21 v4 row-quant verbatim) -> barrier ->
//         phase D = R11 k_d verbatim (ctl_l x khalf, X-frags from LDS rows,
//         W-frags from global Wq, pacc combine, epilogue).
// Integer path bit-exact vs reference. Nx=6272, Ny=128, K=576 (5x116->128).

#define NXROW 6272
#define KDIM  576
#define NPB   116
#define SSTR  656    // LDS row stride: 41*16, b128-aligned; 164 dw % 32 = 4 (2-way, free)

typedef int i32x4 __attribute__((ext_vector_type(4)));

__device__ __forceinline__ i32x4 slice2b(i32x4 v, int sh) {
    i32x4 r;
    r[0] = (int)(((unsigned)v[0] >> sh) & 0x03030303u);
    r[1] = (int)(((unsigned)v[1] >> sh) & 0x03030303u);
    r[2] = (int)(((unsigned)v[2] >> sh) & 0x03030303u);
    r[3] = (int)(((unsigned)v[3] >> sh) & 0x03030303u);
    return r;
}

// v4 row-quant core: lane holds k = r*64+lane (r=0..8). Exact butterfly
// stats; IEEE div quantize; bytes to LDS row at col = k + 12*(k/116).
// Pads zeroed by lane<16 before data writes (same-wave instr order — R21).
__device__ __forceinline__ void rowquant_to_lds(const float (&v)[9],
                                                unsigned char* myrow, int lane,
                                                float* scp, float* ofp, float* smp)
{
    if (lane < 16) {
        int col = lane < 12 ? (lane / 3) * 128 + 116 + (lane % 3) * 4
                            : 624 + (lane - 12) * 4;
        *(unsigned int*)(myrow + col) = 0u;
    }
    float mn = v[0], mx = v[0], s = 0.f;
#pragma unroll
    for (int r = 0; r < 9; r++) { mn = fminf(mn, v[r]); mx = fmaxf(mx, v[r]); s += v[r]; }
#pragma unroll
    for (int off2 = 1; off2 < 64; off2 <<= 1) {
        mn = fminf(mn, __shfl_xor(mn, off2));
        mx = fmaxf(mx, __shfl_xor(mx, off2));
        s += __shfl_xor(s, off2);
    }
    float step = (mx - mn) / 255.0f;      // IEEE — bit-exact vs reference
    if (lane == 0) { *scp = step; *ofp = mn; *smp = s; }
#pragma unroll
    for (int r = 0; r < 9; r++) {
        int q = (int)rintf((v[r] - mn) / step);   // IEEE div — bit-exact
        q = q < 0 ? 0 : (q > 255 ? 255 : q);
        int k = r * 64 + lane;
        int ch = k / NPB;
        myrow[k + 12 * ch] = (unsigned char)q;
    }
}

// ---------------- kernel 1: w quantization (one row per wave) ----------------
__global__ __launch_bounds__(256) void k_wq(
    const float* __restrict__ w, unsigned char* __restrict__ Wq,
    float* __restrict__ wsc, float* __restrict__ wof, float* __restrict__ wsm)
{
    __shared__ __align__(16) unsigned char scr[4][SSTR];
    int tid = threadIdx.x, wv = tid >> 6, lane = tid & 63;
    int row = blockIdx.x * 4 + wv;        // 0..127
    unsigned char* myrow = scr[wv];

    const float* wr = w + (size_t)row * KDIM;
    float v[9];
#pragma unroll
    for (int r = 0; r < 9; r++) v[r] = wr[r * 64 + lane];   // coalesced

    rowquant_to_lds(v, myrow, lane, wsc + row, wof + row, wsm + row);
    __syncthreads();

    // scatter to fragment layout (R21 v4 verbatim)
    if (lane < 40) {
        int u = lane;
        i32x4 seg = *(const i32x4*)(myrow + u * 16);
        int dst16 = (u >> 3) * 128 + ((u >> 2) & 1) * 64 + (u & 3) * 16 + (row & 15);
        *(i32x4*)(Wq + (size_t)(row >> 4) * 10240 + (size_t)dst16 * 16) = seg;
    }
}

// ---------------- kernel 2: fused x-quant + crossbar MFMA + ADC + dequant ----
// one chunk, accumulating into 4 per-ws accumulators (R11 verbatim except
// X-operand from LDS rows: row i16, col ch*128 + ks*64 + g*16 — R8-proven).
__device__ __forceinline__ void chunk_ws(const unsigned char* xp, const unsigned char* wt,
                                         int ch, int lane, i32x4 (&acc4)[4])
{
    const i32x4 zero = {0, 0, 0, 0};
    i32x4 x0 = *(const i32x4*)(xp + ch * 128);
    i32x4 x1 = *(const i32x4*)(xp + ch * 128 + 64);
    i32x4 w0 = *(const i32x4*)(wt + ch * 2048 + lane * 16);
    i32x4 w1 = *(const i32x4*)(wt + ch * 2048 + 1024 + lane * 16);
    i32x4 ws0[4], ws1[4];
#pragma unroll
    for (int ws = 0; ws < 4; ws++) {
        ws0[ws] = slice2b(w0, 6 - 2 * ws);
        ws1[ws] = slice2b(w1, 6 - 2 * ws);
    }
#pragma unroll
    for (int is = 0; is < 4; is++) {
        int ish = 6 - 2 * is;
        i32x4 a0 = slice2b(x0, ish), a1 = slice2b(x1, ish);
#pragma unroll
        for (int ws = 0; ws < 4; ws++) {
            i32x4 d = __builtin_amdgcn_mfma_i32_16x16x64_i8(ws0[ws], a0, zero, 0, 0, 0);
            d = __builtin_amdgcn_mfma_i32_16x16x64_i8(ws1[ws], a1, d, 0, 0, 0);
            int sh = ish + 6 - 2 * ws;
#pragma unroll
            for (int r = 0; r < 4; r++) {
                int z = d[r];
                z = z > 1024 ? 1024 : z;                 // ADC clip (z >= 0)
                int t = (z >> 2) & 1;
                int r4 = (z + 1 + t) & ~3;               // round-half-even, mult of 4
                acc4[ws][r] += r4 << sh;                 // 2^(ish+wsh)
            }
        }
    }
}

__global__ __launch_bounds__(256) void k_main(
    const float* __restrict__ x, const unsigned char* __restrict__ Wq,
    const float* __restrict__ wscg, const float* __restrict__ wofg,
    const float* __restrict__ wsmg, float* __restrict__ out)
{
    __shared__ __align__(16) unsigned char scrX[16 * SSTR];   // 10,496 B
    __shared__ __align__(16) int pacc[2][64][4];
    __shared__ float xscl[16], xofl[16], xsml[16];

    int tid = threadIdx.x, wv = tid >> 6, lane = tid & 63;
    int g = lane >> 4, i16 = lane & 15;
    int blk = blockIdx.x;                 // 0..1567
    int rtile = blk >> 2, cq = blk & 3;   // rtile 0..391, cq 0..3
    int b = rtile >= 196 ? 1 : 0;
    int pos0 = (rtile - 196 * b) * 16;
    const float* xb = x + (size_t)(b * 64) * 3136;

    // ---- x-quant: 4 rows per wave (v4 row-quant, k = r*64+lane)
#pragma unroll
    for (int q = 0; q < 4; q++) {
        int i = wv * 4 + q;               // local row 0..15
        int pos = pos0 + i;
        int hg = pos / 56, wg = pos - hg * 56;
        float v[9];
#pragma unroll
        for (int r = 0; r < 9; r++) {
            int k = r * 64 + lane;
            int cin = k / 9;
            int off = k - cin * 9;        // [cin][kh][kw] (ref im2col order)
            int kh = off / 3;
            int kw = off - kh * 3;
            int hr = hg - 1 + kh, wc = wg - 1 + kw;
            bool ok = ((unsigned)hr < 56u) && ((unsigned)wc < 56u);
            v[r] = ok ? xb[cin * 3136 + hr * 56 + wc] : 0.f;
        }
        rowquant_to_lds(v, scrX + i * SSTR, lane, xscl + i, xofl + i, xsml + i);
    }
    __syncthreads();

    // ---- phase D: wave = (ctl_l = wv&1, khalf = wv>>1); ctile = cq*2+ctl_l
    int ctl_l = wv & 1, khalf = wv >> 1;
    int ct = cq * 2 + ctl_l;
    const unsigned char* xp = scrX + i16 * SSTR + g * 16;
    const unsigned char* wt = Wq + (size_t)ct * 10240;

    i32x4 acc4[4] = {{0,0,0,0},{0,0,0,0},{0,0,0,0},{0,0,0,0}};
    if (khalf == 0) {
        chunk_ws(xp, wt, 0, lane, acc4);
        chunk_ws(xp, wt, 1, lane, acc4);
        chunk_ws(xp, wt, 2, lane, acc4);
    } else {
        chunk_ws(xp, wt, 3, lane, acc4);
        chunk_ws(xp, wt, 4, lane, acc4);
    }
    i32x4 acc;
#pragma unroll
    for (int r = 0; r < 4; r++)
        acc[r] = (acc4[0][r] + acc4[1][r]) + (acc4[2][r] + acc4[3][r]);  // exact

    if (khalf == 0) *(i32x4*)&pacc[ctl_l][lane][0] = acc;
    __syncthreads();

    if (khalf == 1) {
        i32x4 p = *(const i32x4*)&pacc[ctl_l][lane][0];
#pragma unroll
        for (int r = 0; r < 4; r++) acc[r] += p[r];      // chunk-sum, exact

        // epilogue: D[row = w-row (g*4+r), col = x-row (i16)]; 64B coalesced
        float xs_ = xscl[i16], xo = xofl[i16], xsv = xsml[i16];
        int hw = pos0 + i16;
#pragma unroll
        for (int r = 0; r < 4; r++) {
            int wrow = ct * 16 + g * 4 + r;
            float tt = ((float)acc[r] * xs_) * wscg[wrow];
            float res = ((tt + xo * wsmg[wrow]) + wofg[wrow] * xsv)
                      - (xo * wofg[wrow]) * 576.0f;
            out[(size_t)(b * 128 + wrow) * 3136 + hw] = res;
        }
    }
}

extern "C" void kernel_launch(void* const* d_in, const int* in_sizes, int n_in,
                              void* d_out, int out_size, void* d_ws, size_t ws_size,
                              hipStream_t stream) {
    const float* x = (const float*)d_in[0];   // [2][64][56][56]
    const float* w = (const float*)d_in[1];   // [128][64][3][3]
    float* out = (float*)d_out;               // [2][128][56][56]

    unsigned char* Wq = (unsigned char*)d_ws; // 8*10,240 = 81,920 B
    float* wsc = (float*)(Wq + 8 * 10240);
    float* wof = wsc + 128;
    float* wsm = wof + 128;

    hipLaunchKernelGGL(k_wq, dim3(32), dim3(256), 0, stream,
                       w, Wq, wsc, wof, wsm);
    hipLaunchKernelGGL(k_main, dim3(1568), dim3(256), 0, stream,
                       x, Wq, wsc, wof, wsm, out);
}

// Round 23
// 36.326 us; speedup vs baseline: 1.2928x; 1.2928x over previous
//
#include <hip/hip_runtime.h>

// ConvDatapath: bit-serial crossbar conv with per-chunk ADC quantization.
// R21 anchor: k_q 15.3 + k_d 18.6 = 33.9. This round:
// k_q v5: one row per wave, one TILE per block (400 blk x 1024 thr) ->
//         quant to per-wave LDS rows (v3 core, bit-exact), barrier, then
//         FULLY COALESCED fragment-layout store (640 contiguous 16B runs).
// k_d v2: 4-way input-slice split (R18-proven exact): block = 1 tile,
//         wave = is (0..3), 5 chunks x 4 ws each = balanced 40 MFMA/wave;
//         12,544 waves (2x co-residency of R11) hides MFMA->ADC latency;
//         Xq tile staged once in LDS; integer pacc combine; epilogue wave 0.
// Integer path bit-exact vs reference. Nx=6272, Ny=128, K=576 (5x116->128).

#define NXROW 6272
#define KDIM  576
#define NPB   116
#define SSTR  656    // LDS row stride: 41*16, b128-aligned; 164 dw % 32 = 4

typedef int i32x4 __attribute__((ext_vector_type(4)));

__device__ __forceinline__ i32x4 slice2b(i32x4 v, int sh) {
    i32x4 r;
    r[0] = (int)(((unsigned)v[0] >> sh) & 0x03030303u);
    r[1] = (int)(((unsigned)v[1] >> sh) & 0x03030303u);
    r[2] = (int)(((unsigned)v[2] >> sh) & 0x03030303u);
    r[3] = (int)(((unsigned)v[3] >> sh) & 0x03030303u);
    return r;
}

// v4/v3 row-quant core (R20/R21-proven): lane holds k = r*64+lane (r=0..8).
// Exact butterfly stats; IEEE div quantize; bytes to LDS row at
// col = k + 12*(k/116) = ch*128 + k%116; pads zeroed by lane<16 first.
__device__ __forceinline__ void rowquant_to_lds(const float (&v)[9],
                                                unsigned char* myrow, int lane,
                                                float* scp, float* ofp, float* smp)
{
    if (lane < 16) {
        int col = lane < 12 ? (lane / 3) * 128 + 116 + (lane % 3) * 4
                            : 624 + (lane - 12) * 4;
        *(unsigned int*)(myrow + col) = 0u;
    }
    float mn = v[0], mx = v[0], s = 0.f;
#pragma unroll
    for (int r = 0; r < 9; r++) { mn = fminf(mn, v[r]); mx = fmaxf(mx, v[r]); s += v[r]; }
#pragma unroll
    for (int off2 = 1; off2 < 64; off2 <<= 1) {
        mn = fminf(mn, __shfl_xor(mn, off2));
        mx = fmaxf(mx, __shfl_xor(mx, off2));
        s += __shfl_xor(s, off2);
    }
    float step = (mx - mn) / 255.0f;      // IEEE — bit-exact vs reference
    if (lane == 0) { *scp = step; *ofp = mn; *smp = s; }
#pragma unroll
    for (int r = 0; r < 9; r++) {
        int q = (int)rintf((v[r] - mn) / step);   // IEEE div — bit-exact
        q = q < 0 ? 0 : (q > 255 ? 255 : q);
        int k = r * 64 + lane;
        int ch = k / NPB;
        myrow[k + 12 * ch] = (unsigned char)q;
    }
}

// ---------------- kernel 1: quantization (one tile per block) ----------------
// blk < 392: x-tile blk (rows blk*16+wv). blk 392..399: w-tile blk-392.
__global__ __launch_bounds__(1024) void k_q(
    const float* __restrict__ x, const float* __restrict__ w,
    unsigned char* __restrict__ Xq, unsigned char* __restrict__ Wq,
    float* __restrict__ xsc, float* __restrict__ xof, float* __restrict__ xsm,
    float* __restrict__ wsc, float* __restrict__ wof, float* __restrict__ wsm)
{
    __shared__ __align__(16) unsigned char scrT[16][SSTR];   // 10,496 B

    int tid = threadIdx.x, wv = tid >> 6, lane = tid & 63;
    int blk = blockIdx.x;                 // 0..399

    float v[9];
    if (blk < 392) {
        int R = blk * 16 + wv;            // global x-row
        int b = R >= 3136 ? 1 : 0;
        int pos = R - b * 3136;
        int hg = pos / 56, wg = pos - hg * 56;
        const float* xb = x + (size_t)(b * 64) * 3136;
#pragma unroll
        for (int r = 0; r < 9; r++) {
            int k = r * 64 + lane;
            int cin = k / 9;              // magic-mul
            int off = k - cin * 9;        // [cin][kh][kw] (ref im2col order)
            int kh = off / 3;
            int kw = off - kh * 3;
            int hr = hg - 1 + kh, wc = wg - 1 + kw;
            bool ok = ((unsigned)hr < 56u) && ((unsigned)wc < 56u);
            v[r] = ok ? xb[cin * 3136 + hr * 56 + wc] : 0.f;
        }
        rowquant_to_lds(v, scrT[wv], lane, xsc + R, xof + R, xsm + R);
    } else {
        int row = (blk - 392) * 16 + wv;  // 0..127
        const float* wr = w + (size_t)row * KDIM;
#pragma unroll
        for (int r = 0; r < 9; r++) v[r] = wr[r * 64 + lane];   // coalesced
        rowquant_to_lds(v, scrT[wv], lane, wsc + row, wof + row, wsm + row);
    }
    __syncthreads();

    // coalesced fragment-layout store: run dst16 = ch*128+ks*64+lgrp*16+rl,
    // src row rl, col u*16 with u = ch*8 + ks*4 + lgrp (inverse of R21 map).
    unsigned char* dst = blk < 392 ? Xq + (size_t)blk * 10240
                                   : Wq + (size_t)(blk - 392) * 10240;
    if (tid < 640) {
        int rl = tid & 15;
        int u = (tid >> 7) * 8 + ((tid >> 6) & 1) * 4 + ((tid >> 4) & 3);
        *(i32x4*)(dst + (size_t)tid * 16) = *(const i32x4*)(&scrT[rl][u * 16]);
    }
}

// ---------------- kernel 2: crossbar MFMA + ADC + dequant (4-way is-split) --
__global__ __launch_bounds__(256) void k_d(
    const unsigned char* __restrict__ Xq, const unsigned char* __restrict__ Wq,
    const float* __restrict__ xscg, const float* __restrict__ xofg,
    const float* __restrict__ xsmg,
    const float* __restrict__ wscg, const float* __restrict__ wofg,
    const float* __restrict__ wsmg, float* __restrict__ out)
{
    __shared__ __align__(16) unsigned char xlds[10240];
    __shared__ __align__(16) int pacc[4][64][4];

    int tid = threadIdx.x, wv = tid >> 6, lane = tid & 63;
    int g = lane >> 4, i16 = lane & 15;
    int blk = blockIdx.x;                 // 0..3135
    int ct = blk & 7, rtile = blk >> 3;   // one output tile per block
    const unsigned char* xt = Xq + (size_t)rtile * 10240;
    const unsigned char* wt = Wq + (size_t)ct * 10240;

    // stage Xq tile into LDS (coalesced 16B runs; read 4x by the 4 waves)
    for (int idx = tid; idx < 640; idx += 256)
        *(i32x4*)(xlds + (size_t)idx * 16) = *(const i32x4*)(xt + (size_t)idx * 16);
    __syncthreads();

    // wave wv = input-slice is; 5 chunks x 4 ws = 40 MFMA-pairs, balanced.
    int ish = 6 - 2 * wv;                 // wave-uniform
    const i32x4 zero = {0, 0, 0, 0};
    i32x4 acc4[4] = {{0,0,0,0},{0,0,0,0},{0,0,0,0},{0,0,0,0}};

#pragma unroll
    for (int ch = 0; ch < 5; ch++) {
        i32x4 x0 = *(const i32x4*)(xlds + ch * 2048 + lane * 16);
        i32x4 x1 = *(const i32x4*)(xlds + ch * 2048 + 1024 + lane * 16);
        i32x4 w0 = *(const i32x4*)(wt + ch * 2048 + lane * 16);
        i32x4 w1 = *(const i32x4*)(wt + ch * 2048 + 1024 + lane * 16);
        i32x4 a0 = slice2b(x0, ish), a1 = slice2b(x1, ish);
#pragma unroll
        for (int ws = 0; ws < 4; ws++) {
            i32x4 b0 = slice2b(w0, 6 - 2 * ws);
            i32x4 b1 = slice2b(w1, 6 - 2 * ws);
            i32x4 d = __builtin_amdgcn_mfma_i32_16x16x64_i8(b0, a0, zero, 0, 0, 0);
            d = __builtin_amdgcn_mfma_i32_16x16x64_i8(b1, a1, d, 0, 0, 0);
            int sh = ish + 6 - 2 * ws;
#pragma unroll
            for (int r = 0; r < 4; r++) {
                int z = d[r];
                z = z > 1024 ? 1024 : z;                 // ADC clip (z >= 0)
                int t = (z >> 2) & 1;
                int r4 = (z + 1 + t) & ~3;               // round-half-even, mult of 4
                acc4[ws][r] += r4 << sh;                 // 2^(ish+wsh)
            }
        }
    }

    i32x4 acc;
#pragma unroll
    for (int r = 0; r < 4; r++)
        acc[r] = (acc4[0][r] + acc4[1][r]) + (acc4[2][r] + acc4[3][r]);  // exact

    if (wv != 0) *(i32x4*)&pacc[wv][lane][0] = acc;
    __syncthreads();

    if (wv == 0) {
        i32x4 p1 = *(const i32x4*)&pacc[1][lane][0];
        i32x4 p2 = *(const i32x4*)&pacc[2][lane][0];
        i32x4 p3 = *(const i32x4*)&pacc[3][lane][0];
#pragma unroll
        for (int r = 0; r < 4; r++)
            acc[r] = (acc[r] + p1[r]) + (p2[r] + p3[r]);   // is-sum, exact

        // epilogue: D[row = w-row (g*4+r), col = x-row (i16)]; 64B coalesced
        int b = rtile >= 196 ? 1 : 0;
        int xrow = rtile * 16 + i16;
        float xs_ = xscg[xrow], xo = xofg[xrow], xsv = xsmg[xrow];
        int hw = (rtile - 196 * b) * 16 + i16;
#pragma unroll
        for (int r = 0; r < 4; r++) {
            int wrow = ct * 16 + g * 4 + r;
            float tt = ((float)acc[r] * xs_) * wscg[wrow];
            float res = ((tt + xo * wsmg[wrow]) + wofg[wrow] * xsv)
                      - (xo * wofg[wrow]) * 576.0f;
            out[(size_t)(b * 128 + wrow) * 3136 + hw] = res;
        }
    }
}

extern "C" void kernel_launch(void* const* d_in, const int* in_sizes, int n_in,
                              void* d_out, int out_size, void* d_ws, size_t ws_size,
                              hipStream_t stream) {
    const float* x = (const float*)d_in[0];   // [2][64][56][56]
    const float* w = (const float*)d_in[1];   // [128][64][3][3]
    float* out = (float*)d_out;               // [2][128][56][56]

    unsigned char* Xq = (unsigned char*)d_ws;          // 392*10,240 = 4,014,080 B
    unsigned char* Wq = Xq + (size_t)392 * 10240;      // 8*10,240   = 81,920 B
    float* xsc = (float*)(Wq + 8 * 10240);
    float* xof = xsc + NXROW;
    float* xsm = xof + NXROW;
    float* wsc = xsm + NXROW;
    float* wof = wsc + 128;
    float* wsm = wof + 128;

    hipLaunchKernelGGL(k_q, dim3(400), dim3(1024), 0, stream,
                       x, w, Xq, Wq, xsc, xof, xsm, wsc, wof, wsm);
    hipLaunchKernelGGL(k_d, dim3(3136), dim3(256), 0, stream,
                       Xq, Wq, xsc, xof, xsm, wsc, wof, wsm, out);
}

// Round 24
// 34.056 us; speedup vs baseline: 1.3790x; 1.0667x over previous
//
#include <hip/hip_runtime.h>

// ConvDatapath: bit-serial crossbar conv with per-chunk ADC quantization.
// R21 anchor 33.9 = k_q v4 15.3 + k_d R11 18.6. R23 (bundled) regressed.
// This round: ONE change — k_q v4 verbatim; k_d v3 = 4-way input-slice split
// (R18-proven exact) at 3136 blocks (12.25 waves/SIMD, 2x R11) with DIRECT
// global fragment reads (no LDS staging — R11 proved L2 absorbs reuse).
// Integer path bit-exact vs reference. Nx=6272, Ny=128, K=576 (5x116->128).

#define NXROW 6272
#define KDIM  576
#define NPB   116
#define SSTR  656    // LDS row stride: 41*16, b128-aligned; 164 dw % 32 = 4

typedef int i32x4 __attribute__((ext_vector_type(4)));

__device__ __forceinline__ i32x4 slice2b(i32x4 v, int sh) {
    i32x4 r;
    r[0] = (int)(((unsigned)v[0] >> sh) & 0x03030303u);
    r[1] = (int)(((unsigned)v[1] >> sh) & 0x03030303u);
    r[2] = (int)(((unsigned)v[2] >> sh) & 0x03030303u);
    r[3] = (int)(((unsigned)v[3] >> sh) & 0x03030303u);
    return r;
}

// ---------------- kernel 1: quantization, one row per wave (R21 verbatim) ---
__global__ __launch_bounds__(256) void k_q(
    const float* __restrict__ x, const float* __restrict__ w,
    unsigned char* __restrict__ Xq, unsigned char* __restrict__ Wq,
    float* __restrict__ xsc, float* __restrict__ xof, float* __restrict__ xsm,
    float* __restrict__ wsc, float* __restrict__ wof, float* __restrict__ wsm)
{
    __shared__ __align__(16) unsigned char scr[4][SSTR];  // per-wave row

    int tid = threadIdx.x, wv = tid >> 6, lane = tid & 63;
    int W = blockIdx.x * 4 + wv;          // 0..6399, wave-uniform
    unsigned char* myrow = scr[wv];

    if (lane < 16) {
        int col = lane < 12 ? (lane / 3) * 128 + 116 + (lane % 3) * 4
                            : 624 + (lane - 12) * 4;
        *(unsigned int*)(myrow + col) = 0u;
    }

    float v[9];
    unsigned char* dstbase;
    int rl;
    float *sc, *of, *sm;
    int sidx;

    if (W < NXROW) {
        int b = W >= 3136 ? 1 : 0;
        int pos = W - b * 3136;
        int hg = pos / 56, wg = pos - hg * 56;
        const float* xb = x + (size_t)(b * 64) * 3136;
#pragma unroll
        for (int r = 0; r < 9; r++) {
            int k = r * 64 + lane;
            int cin = k / 9;              // magic-mul
            int off = k - cin * 9;        // [cin][kh][kw] (ref im2col order)
            int kh = off / 3;
            int kw = off - kh * 3;
            int hr = hg - 1 + kh, wc = wg - 1 + kw;
            bool ok = ((unsigned)hr < 56u) && ((unsigned)wc < 56u);
            v[r] = ok ? xb[cin * 3136 + hr * 56 + wc] : 0.f;
        }
        dstbase = Xq + (size_t)(W >> 4) * 10240;  rl = W & 15;
        sc = xsc; of = xof; sm = xsm; sidx = W;
    } else {
        int row = W - NXROW;              // 0..127
        const float* wr = w + (size_t)row * KDIM;
#pragma unroll
        for (int r = 0; r < 9; r++) v[r] = wr[r * 64 + lane];
        dstbase = Wq + (size_t)(row >> 4) * 10240;  rl = row & 15;
        sc = wsc; of = wof; sm = wsm; sidx = row;
    }

    float mn = v[0], mx = v[0], s = 0.f;
#pragma unroll
    for (int r = 0; r < 9; r++) { mn = fminf(mn, v[r]); mx = fmaxf(mx, v[r]); s += v[r]; }
#pragma unroll
    for (int off2 = 1; off2 < 64; off2 <<= 1) {
        mn = fminf(mn, __shfl_xor(mn, off2));
        mx = fmaxf(mx, __shfl_xor(mx, off2));
        s += __shfl_xor(s, off2);
    }
    float step = (mx - mn) / 255.0f;      // IEEE — bit-exact vs reference
    if (lane == 0) { sc[sidx] = step; of[sidx] = mn; sm[sidx] = s; }

#pragma unroll
    for (int r = 0; r < 9; r++) {
        int q = (int)rintf((v[r] - mn) / step);   // IEEE div — bit-exact
        q = q < 0 ? 0 : (q > 255 ? 255 : q);
        int k = r * 64 + lane;
        int ch = k / NPB;
        myrow[k + 12 * ch] = (unsigned char)q;
    }
    __syncthreads();   // uniform: orders LDS byte-writes before segment reads

    if (lane < 40) {
        int u = lane;
        i32x4 seg = *(const i32x4*)(myrow + u * 16);
        int dst16 = (u >> 3) * 128 + ((u >> 2) & 1) * 64 + (u & 3) * 16 + rl;
        *(i32x4*)(dstbase + (size_t)dst16 * 16) = seg;
    }
}

// ---------------- kernel 2: crossbar MFMA + ADC + dequant (is-split v3) -----
// block = output tile (3136); wave = input-slice is; direct global frags.
__global__ __launch_bounds__(256) void k_d(
    const unsigned char* __restrict__ Xq, const unsigned char* __restrict__ Wq,
    const float* __restrict__ xscg, const float* __restrict__ xofg,
    const float* __restrict__ xsmg,
    const float* __restrict__ wscg, const float* __restrict__ wofg,
    const float* __restrict__ wsmg, float* __restrict__ out)
{
    __shared__ __align__(16) int pacc[4][64][4];

    int tid = threadIdx.x, wv = tid >> 6, lane = tid & 63;
    int g = lane >> 4, i16 = lane & 15;
    int blk = blockIdx.x;                 // 0..3135
    int ct = blk & 7, rtile = blk >> 3;
    const unsigned char* xt = Xq + (size_t)rtile * 10240 + lane * 16;
    const unsigned char* wt = Wq + (size_t)ct * 10240 + lane * 16;

    int ish = 6 - 2 * wv;                 // wave-uniform input-slice shift
    const i32x4 zero = {0, 0, 0, 0};
    i32x4 acc4[4] = {{0,0,0,0},{0,0,0,0},{0,0,0,0},{0,0,0,0}};

#pragma unroll
    for (int ch = 0; ch < 5; ch++) {
        i32x4 x0 = *(const i32x4*)(xt + ch * 2048);
        i32x4 x1 = *(const i32x4*)(xt + ch * 2048 + 1024);
        i32x4 w0 = *(const i32x4*)(wt + ch * 2048);
        i32x4 w1 = *(const i32x4*)(wt + ch * 2048 + 1024);
        i32x4 a0 = slice2b(x0, ish), a1 = slice2b(x1, ish);
#pragma unroll
        for (int ws = 0; ws < 4; ws++) {
            i32x4 b0 = slice2b(w0, 6 - 2 * ws);
            i32x4 b1 = slice2b(w1, 6 - 2 * ws);
            i32x4 d = __builtin_amdgcn_mfma_i32_16x16x64_i8(b0, a0, zero, 0, 0, 0);
            d = __builtin_amdgcn_mfma_i32_16x16x64_i8(b1, a1, d, 0, 0, 0);
            int sh = ish + 6 - 2 * ws;
#pragma unroll
            for (int r = 0; r < 4; r++) {
                int z = d[r];
                z = z > 1024 ? 1024 : z;                 // ADC clip (z >= 0)
                int t = (z >> 2) & 1;
                int r4 = (z + 1 + t) & ~3;               // round-half-even, mult of 4
                acc4[ws][r] += r4 << sh;                 // 2^(ish+wsh)
            }
        }
    }

    i32x4 acc;
#pragma unroll
    for (int r = 0; r < 4; r++)
        acc[r] = (acc4[0][r] + acc4[1][r]) + (acc4[2][r] + acc4[3][r]);  // exact

    if (wv != 0) *(i32x4*)&pacc[wv][lane][0] = acc;
    __syncthreads();

    if (wv == 0) {
        i32x4 p1 = *(const i32x4*)&pacc[1][lane][0];
        i32x4 p2 = *(const i32x4*)&pacc[2][lane][0];
        i32x4 p3 = *(const i32x4*)&pacc[3][lane][0];
#pragma unroll
        for (int r = 0; r < 4; r++)
            acc[r] = (acc[r] + p1[r]) + (p2[r] + p3[r]);   // is-sum, exact

        // epilogue: D[row = w-row (g*4+r), col = x-row (i16)]; 64B coalesced
        int b = rtile >= 196 ? 1 : 0;
        int xrow = rtile * 16 + i16;
        float xs_ = xscg[xrow], xo = xofg[xrow], xsv = xsmg[xrow];
        int hw = (rtile - 196 * b) * 16 + i16;
#pragma unroll
        for (int r = 0; r < 4; r++) {
            int wrow = ct * 16 + g * 4 + r;
            float tt = ((float)acc[r] * xs_) * wscg[wrow];
            float res = ((tt + xo * wsmg[wrow]) + wofg[wrow] * xsv)
                      - (xo * wofg[wrow]) * 576.0f;
            out[(size_t)(b * 128 + wrow) * 3136 + hw] = res;
        }
    }
}

extern "C" void kernel_launch(void* const* d_in, const int* in_sizes, int n_in,
                              void* d_out, int out_size, void* d_ws, size_t ws_size,
                              hipStream_t stream) {
    const float* x = (const float*)d_in[0];   // [2][64][56][56]
    const float* w = (const float*)d_in[1];   // [128][64][3][3]
    float* out = (float*)d_out;               // [2][128][56][56]

    unsigned char* Xq = (unsigned char*)d_ws;          // 392*10,240 = 4,014,080 B
    unsigned char* Wq = Xq + (size_t)392 * 10240;      // 8*10,240   = 81,920 B
    float* xsc = (float*)(Wq + 8 * 10240);
    float* xof = xsc + NXROW;
    float* xsm = xof + NXROW;
    float* wsc = xsm + NXROW;
    float* wof = wsc + 128;
    float* wsm = wof + 128;

    hipLaunchKernelGGL(k_q, dim3(1600), dim3(256), 0, stream,
                       x, w, Xq, Wq, xsc, xof, xsm, wsc, wof, wsm);
    hipLaunchKernelGGL(k_d, dim3(3136), dim3(256), 0, stream,
                       Xq, Wq, xsc, xof, xsm, wsc, wof, wsm, out);
}